// Round 4
// baseline (332.325 us; speedup 1.0000x reference)
//
#include <hip/hip_runtime.h>
#include <hip/hip_bf16.h>
#include <hip/hip_fp16.h>

typedef _Float16 half8 __attribute__((ext_vector_type(8)));
typedef float f32x4 __attribute__((ext_vector_type(4)));

#define GM 32768
#define GN 1024
#define GK 1024
#define NKT 16            // K-tiles of 64
#define NIT 8             // iterations, 2 K-tiles each

// LDS: slot(d, T, kh) = d*65536 + T*32768 + kh*16384 ; T: A=0, B=1
// each slot: [256 rows][32 k] f16 = 16 KB (rows 0-127 bytes 0-8191, 128-255 above)
#define LDS_BYTES 131072

#define AX_BLOCKS 2048
#define AW_BLOCKS 64
#define QX_BLOCKS 16384
#define QW_BLOCKS 512

__device__ __forceinline__ float fp8_scale_from_amax(float amax) {
    float s = 448.0f / (amax * 2.0f + 1e-12f);
    return fminf(fmaxf(s, 1e-12f), 1e12f);
}

// ---------------- amax partials (fused x / w) — no atomics ----------------
__global__ __launch_bounds__(256) void amax_kernel(const float4* __restrict__ x,
                                                   const float4* __restrict__ w,
                                                   float* __restrict__ px,
                                                   float* __restrict__ pw) {
    __shared__ float red[4];
    int b = blockIdx.x;
    const float4* src; float* dst; int nb, bl;
    if (b < AX_BLOCKS) { src = x; dst = px + b; nb = AX_BLOCKS; bl = b; }
    else               { src = w; dst = pw + (b - AX_BLOCKS); nb = AW_BLOCKS; bl = b - AX_BLOCKS; }
    const size_t stride = (size_t)nb * 256;
    const float4* p = src + (size_t)bl * 256 + threadIdx.x;
    float m0 = 0.f, m1 = 0.f, m2 = 0.f, m3 = 0.f;
    #pragma unroll
    for (int j = 0; j < 4; ++j) {
        float4 a = p[0];
        float4 c = p[stride];
        float4 d = p[2 * stride];
        float4 e = p[3 * stride];
        p += 4 * stride;
        m0 = fmaxf(m0, fmaxf(fmaxf(fabsf(a.x), fabsf(a.y)), fmaxf(fabsf(a.z), fabsf(a.w))));
        m1 = fmaxf(m1, fmaxf(fmaxf(fabsf(c.x), fabsf(c.y)), fmaxf(fabsf(c.z), fabsf(c.w))));
        m2 = fmaxf(m2, fmaxf(fmaxf(fabsf(d.x), fabsf(d.y)), fmaxf(fabsf(d.z), fabsf(d.w))));
        m3 = fmaxf(m3, fmaxf(fmaxf(fabsf(e.x), fabsf(e.y)), fmaxf(fabsf(e.z), fabsf(e.w))));
    }
    float m = fmaxf(fmaxf(m0, m1), fmaxf(m2, m3));
    #pragma unroll
    for (int off = 32; off; off >>= 1) m = fmaxf(m, __shfl_xor(m, off));
    const int lane = threadIdx.x & 63, wid = threadIdx.x >> 6;
    if (lane == 0) red[wid] = m;
    __syncthreads();
    if (threadIdx.x == 0)
        *dst = fmaxf(fmaxf(red[0], red[1]), fmaxf(red[2], red[3]));
}

__global__ __launch_bounds__(256) void reduce_kernel(const float* __restrict__ px,
                                                     const float* __restrict__ pw,
                                                     unsigned* __restrict__ amax_bits) {
    __shared__ float red[8];
    const int tid = threadIdx.x, lane = tid & 63, wid = tid >> 6;
    float mx = 0.f;
    for (int i = tid; i < AX_BLOCKS; i += 256) mx = fmaxf(mx, px[i]);
    #pragma unroll
    for (int off = 32; off; off >>= 1) mx = fmaxf(mx, __shfl_xor(mx, off));
    if (lane == 0) red[wid] = mx;
    float mw = (tid < AW_BLOCKS) ? pw[tid] : 0.f;
    #pragma unroll
    for (int off = 32; off; off >>= 1) mw = fmaxf(mw, __shfl_xor(mw, off));
    if (tid == 0) red[4] = mw;
    __syncthreads();
    if (tid == 0) {
        float a = fmaxf(fmaxf(red[0], red[1]), fmaxf(red[2], red[3]));
        amax_bits[0] = __float_as_uint(a);
        amax_bits[1] = __float_as_uint(red[4]);
    }
}

// ---------------- quantize: X8 = rint(clip(x*s,±448)*8) as exact-int f16 ----------------
__global__ __launch_bounds__(256) void quant_kernel(const float* __restrict__ x,
                                                    const float* __restrict__ w,
                                                    _Float16* __restrict__ X8,
                                                    _Float16* __restrict__ W8,
                                                    const unsigned* __restrict__ amax_bits) {
    int b = blockIdx.x;
    const float* src; _Float16* dst; int bl; int slot;
    if (b < QX_BLOCKS) { src = x; dst = X8; bl = b; slot = 0; }
    else               { src = w; dst = W8; bl = b - QX_BLOCKS; slot = 1; }
    float amax  = __uint_as_float(amax_bits[slot]);
    float scale = fp8_scale_from_amax(amax);
    size_t base = ((size_t)bl * 256 + threadIdx.x) * 8;
    float4 v0 = *(const float4*)(src + base);
    float4 v1 = *(const float4*)(src + base + 4);
    float vs[8] = {v0.x, v0.y, v0.z, v0.w, v1.x, v1.y, v1.z, v1.w};
    half8 h;
    #pragma unroll
    for (int j = 0; j < 8; ++j) {
        float s = vs[j] * scale;
        s = fminf(fmaxf(s, -448.0f), 448.0f);
        h[j] = (_Float16)rintf(s * 8.0f);
    }
    *(half8*)(dst + base) = h;
}

// ---------------- GEMM: 256^2 tile, BK=64, 8-phase schedule (T2+T3+T4+T5) ------
// 512 thr (8 waves 2Mx4N, per-wave 128x64). Iteration j computes K-tiles 2j (buf d0)
// and 2j+1 (buf d1), 8 phases of {ds_read subtile | stage half-tile | bar | 16 MFMA | bar}.
// Stage ledger (steady state, iter j) — slot staged 1 phase after its last read,
// covered by vmcnt(6)+barrier checkpoint (>=3 half-tiles staged after) before its read:
//   p0: d1.A.k1 <- kt 2j+1 [read p6,p7; ckpt end-p3]   p4: d0.A.k1 <- kt 2j+2 [read j+1 p2,p3; ckpt end-p7]
//   p1: d0.B.k0 <- kt 2j+2 [read j+1 p0; ckpt end-p7]  p5: d1.B.k0 <- kt 2j+3 [read j+1 p4; ckpt j+1 end-p3]
//   p2: d0.A.k0 <- kt 2j+2 [read j+1 p0,p1; " ]        p6: d1.A.k0 <- kt 2j+3 [read j+1 p4,p5; " ]
//   p3: d0.B.k1 <- kt 2j+2 [read j+1 p2; " ]           p7: d1.B.k1 <- kt 2j+3 [read j+1 p6; " ]
// Compute: p0..p3 = d0 (ks0 mh0, ks0 mh1, ks1 mh0, ks1 mh1); p4..p7 = d1 same.
// vmcnt(6) ONLY at end of p3 and p7 (never 0 in main loop). Last-iter stage sources
// clamp kt to 15 (must keep issuing: skipping breaks vmcnt counting).
__global__ __launch_bounds__(512, 2) void gemm_kernel(const _Float16* __restrict__ A,  // [GM][GK]
                                                      const _Float16* __restrict__ B,  // [GN][GK]
                                                      const float* __restrict__ bias,
                                                      float* __restrict__ C,
                                                      const unsigned* __restrict__ amax_bits) {
    extern __shared__ char lds[];

    const int tid  = threadIdx.x;
    const int wid  = tid >> 6;
    const int lane = tid & 63;
    const int wr   = wid >> 2;      // 0..1
    const int wc   = wid & 3;       // 0..3
    const int l16  = lane & 15;
    const int kq   = lane >> 4;     // k-chunk group 0..3

    // XCD swizzle: 512 blocks = 8 XCD x 64; bn fast within chunk (A-panel reuse)
    const int bid = blockIdx.x;
    const int swz = (bid & 7) * 64 + (bid >> 3);
    const int bm  = swz >> 2;       // 0..127
    const int bn  = swz & 3;        // 0..3
    const int row0 = bm * 256, col0 = bn * 256;

    // staging: thread covers (row r, physical chunk ch); logical k-chunk kl = ch ^ ((r>>1)&3)
    const int r    = tid >> 2;                 // 0..127
    const int ch   = tid & 3;
    const int kl   = ch ^ ((r >> 1) & 3);
    const _Float16* gA = A + (size_t)(row0 + r) * GK + kl * 8;
    const _Float16* gB = B + (size_t)(col0 + r) * GK + kl * 8;
    const int dstoff = wid * 1024;             // HW adds lane*16

    // ds_read: physical chunk for logical kq at frag rows = kq ^ ((l16>>1)&3)
    const int rsw  = (kq ^ ((l16 >> 1) & 3)) << 4;
    const int aoff = (wr * 128 + l16) * 64 + rsw;   // + mh*4096 + mi*1024
    const int boff = (wc * 64 + l16) * 64 + rsw;    // + n*1024

    f32x4 acc[8][4] = {};
    half8 bf0, bf1, bf2, bf3, a0, a1, a2, a3;

#define STAGE(d, T, kh, kt, g) do {                                                     \
    const _Float16* s_ = (g) + (size_t)(kt) * 64 + (kh) * 32;                           \
    char* dst_ = lds + (d) * 65536 + (T) * 32768 + (kh) * 16384 + dstoff;               \
    __builtin_amdgcn_global_load_lds((const __attribute__((address_space(1))) void*)s_, \
        (__attribute__((address_space(3))) void*)dst_, 16, 0, 0);                       \
    __builtin_amdgcn_global_load_lds(                                                   \
        (const __attribute__((address_space(1))) void*)(s_ + (size_t)128 * GK),         \
        (__attribute__((address_space(3))) void*)(dst_ + 8192), 16, 0, 0);              \
} while (0)

#define RD_B(d, ks) do { const char* p_ = lds + (d) * 65536 + 32768 + (ks) * 16384;     \
    bf0 = *(const half8*)(p_ + boff);        bf1 = *(const half8*)(p_ + boff + 1024);   \
    bf2 = *(const half8*)(p_ + boff + 2048); bf3 = *(const half8*)(p_ + boff + 3072); } while (0)

#define RD_A(d, ks, mh) do { const char* p_ = lds + (d) * 65536 + (ks) * 16384 + (mh) * 4096; \
    a0 = *(const half8*)(p_ + aoff);         a1 = *(const half8*)(p_ + aoff + 1024);    \
    a2 = *(const half8*)(p_ + aoff + 2048);  a3 = *(const half8*)(p_ + aoff + 3072); } while (0)

#define MM4(f, av)                                                                      \
    acc[f][0] = __builtin_amdgcn_mfma_f32_16x16x32_f16(av, bf0, acc[f][0], 0, 0, 0);    \
    acc[f][1] = __builtin_amdgcn_mfma_f32_16x16x32_f16(av, bf1, acc[f][1], 0, 0, 0);    \
    acc[f][2] = __builtin_amdgcn_mfma_f32_16x16x32_f16(av, bf2, acc[f][2], 0, 0, 0);    \
    acc[f][3] = __builtin_amdgcn_mfma_f32_16x16x32_f16(av, bf3, acc[f][3], 0, 0, 0);

#define MFMA16(mh) do { __builtin_amdgcn_s_setprio(1);                                  \
    MM4((mh) * 4 + 0, a0) MM4((mh) * 4 + 1, a1)                                         \
    MM4((mh) * 4 + 2, a2) MM4((mh) * 4 + 3, a3)                                         \
    __builtin_amdgcn_s_setprio(0); } while (0)

#define BAR() do { asm volatile("" ::: "memory"); __builtin_amdgcn_s_barrier();         \
                   asm volatile("" ::: "memory"); } while (0)
#define CKPT() asm volatile("s_waitcnt vmcnt(6)" ::: "memory")

    // ---- prologue: steady-state issue order "p1..p7 of iter -1"
    STAGE(0, 1, 0, 0, gB);   // d0.B.k0  kt0
    STAGE(0, 0, 0, 0, gA);   // d0.A.k0  kt0
    STAGE(0, 1, 1, 0, gB);   // d0.B.k1  kt0
    STAGE(0, 0, 1, 0, gA);   // d0.A.k1  kt0
    STAGE(1, 1, 0, 1, gB);   // d1.B.k0  kt1
    STAGE(1, 0, 0, 1, gA);   // d1.A.k0  kt1
    STAGE(1, 1, 1, 1, gB);   // d1.B.k1  kt1
    CKPT();                  // 14 loads out, wait to 6 -> d0 fully landed
    BAR();

    for (int j = 0; j < NIT; ++j) {
        const int kt1 = 2 * j + 1;
        const int kn0 = (2 * j + 2 < NKT - 1) ? 2 * j + 2 : NKT - 1;
        const int kn1 = (2 * j + 3 < NKT - 1) ? 2 * j + 3 : NKT - 1;
        // p0
        RD_B(0, 0); RD_A(0, 0, 0); STAGE(1, 0, 1, kt1, gA);
        BAR(); MFMA16(0); BAR();
        // p1
        RD_A(0, 0, 1); STAGE(0, 1, 0, kn0, gB);
        BAR(); MFMA16(1); BAR();
        // p2
        RD_B(0, 1); RD_A(0, 1, 0); STAGE(0, 0, 0, kn0, gA);
        BAR(); MFMA16(0); BAR();
        // p3
        RD_A(0, 1, 1); STAGE(0, 1, 1, kn0, gB); CKPT();
        BAR(); MFMA16(1); BAR();
        // p4
        RD_B(1, 0); RD_A(1, 0, 0); STAGE(0, 0, 1, kn0, gA);
        BAR(); MFMA16(0); BAR();
        // p5
        RD_A(1, 0, 1); STAGE(1, 1, 0, kn1, gB);
        BAR(); MFMA16(1); BAR();
        // p6
        RD_B(1, 1); RD_A(1, 1, 0); STAGE(1, 0, 0, kn1, gA);
        BAR(); MFMA16(0); BAR();
        // p7
        RD_A(1, 1, 1); STAGE(1, 1, 1, kn1, gB); CKPT();
        BAR(); MFMA16(1); BAR();
    }

#undef STAGE
#undef RD_B
#undef RD_A
#undef MM4
#undef MFMA16
#undef BAR
#undef CKPT

    // ---- epilogue: out = acc / (64 * a_scale * w_scale) + bias
    float sa = fp8_scale_from_amax(__uint_as_float(amax_bits[0]));
    float sw = fp8_scale_from_amax(__uint_as_float(amax_bits[1]));
    float rs = 1.0f / (64.0f * sa * sw);

    const int orow = row0 + wr * 128 + kq * 4;
    const int ocol = col0 + wc * 64 + l16;
    float bvv[4];
    #pragma unroll
    for (int n = 0; n < 4; ++n) bvv[n] = bias[ocol + n * 16];
    #pragma unroll
    for (int f = 0; f < 8; ++f) {
        #pragma unroll
        for (int n = 0; n < 4; ++n) {
            const int cc = ocol + n * 16;
            #pragma unroll
            for (int i = 0; i < 4; ++i) {
                const int rr = orow + f * 16 + i;
                C[(size_t)rr * GN + cc] = acc[f][n][i] * rs + bvv[n];
            }
        }
    }
}

extern "C" void kernel_launch(void* const* d_in, const int* in_sizes, int n_in,
                              void* d_out, int out_size, void* d_ws, size_t ws_size,
                              hipStream_t stream) {
    const float* x    = (const float*)d_in[0];  // [32768][1024]
    const float* w    = (const float*)d_in[1];  // [1024][1024]
    const float* bias = (const float*)d_in[2];  // [1024]
    float* out        = (float*)d_out;          // [32768][1024]

    unsigned* amax_bits = (unsigned*)d_ws;                       // 2 u32
    float* px = (float*)((char*)d_ws + 4096);                    // 2048 partials
    float* pw = px + AX_BLOCKS;                                  // 64 partials
    _Float16* X8 = (_Float16*)((char*)d_ws + 65536);
    _Float16* W8 = (_Float16*)((char*)d_ws + 65536 + (size_t)GM * GK * 2);

    amax_kernel<<<AX_BLOCKS + AW_BLOCKS, 256, 0, stream>>>(
        (const float4*)x, (const float4*)w, px, pw);

    reduce_kernel<<<1, 256, 0, stream>>>(px, pw, amax_bits);

    quant_kernel<<<QX_BLOCKS + QW_BLOCKS, 256, 0, stream>>>(x, w, X8, W8, amax_bits);

    (void)hipFuncSetAttribute((const void*)gemm_kernel,
                              hipFuncAttributeMaxDynamicSharedMemorySize, LDS_BYTES);
    gemm_kernel<<<(GM / 256) * (GN / 256), 512, LDS_BYTES, stream>>>(X8, W8, bias, out, amax_bits);
}